// Round 2
// baseline (10186.361 us; speedup 1.0000x reference)
//
#include <hip/hip_runtime.h>

typedef unsigned short u16;
typedef unsigned int u32;
typedef __attribute__((ext_vector_type(8))) short short8v;   // 8 bf16 (4 VGPR) MFMA frag
typedef __attribute__((ext_vector_type(4))) float f32x4;     // MFMA acc
typedef __attribute__((ext_vector_type(8))) u16 ush8;
typedef __attribute__((ext_vector_type(4))) u16 ush4;

__device__ __forceinline__ u16 f2bf(float x) {               // RNE f32->bf16
  u32 u = __builtin_bit_cast(u32, x);
  return (u16)((u + 0x7FFFu + ((u >> 16) & 1u)) >> 16);
}
__device__ __forceinline__ float bf2f(u16 h) {
  u32 u = ((u32)h) << 16;
  return __builtin_bit_cast(float, u);
}
__device__ __forceinline__ float sigm(float x) { return 1.f / (1.f + expf(-x)); }

typedef const __attribute__((address_space(1))) void gv_t;
typedef __attribute__((address_space(3))) void lv_t;
__device__ __forceinline__ void gload16(const void* g, void* l) {
  __builtin_amdgcn_global_load_lds((gv_t*)g, (lv_t*)l, 16, 0, 0);
}

// ---------------------------------------------------------------------------
// ConvLSTM recurrence: one WG per (b, row). Computes h for all t, stores
// split-bf16 h_vec rows [t*16+b][4096].  d = r*256 + ch*16 + col.
// ---------------------------------------------------------------------------
__global__ __launch_bounds__(256) void k_conv(int cin, int xmode,
    const float* __restrict__ xin, const float* __restrict__ cw,
    const float* __restrict__ cb, u16* __restrict__ hhi, u16* __restrict__ hlo)
{
  __shared__ float zb[32 * 18];        // cin x (16+2 pad)
  __shared__ float wb[64 * 32 * 3];
  __shared__ float bb[64];
  const int tid = threadIdx.x;
  const int b = blockIdx.x >> 4, r = blockIdx.x & 15;
  const int ch = tid >> 4, col = tid & 15;
  const int cx = cin - 16;
  for (int i = tid; i < 64 * cin * 3; i += 256) wb[i] = cw[i];
  if (tid < 64) bb[tid] = cb[tid];
  for (int i = tid; i < cin * 18; i += 256) zb[i] = 0.f;  // includes pad cols
  __syncthreads();
  float h = 0.f, c = 0.f;
  for (int t = 0; t < 128; ++t) {
    if (xmode == 0) {
      if (ch == 0) zb[col + 1] = xin[((long)b * 128 + t) * 256 + r * 16 + col];
    } else {
      zb[ch * 18 + col + 1] = xin[((long)t * 16 + b) * 4096 + r * 256 + ch * 16 + col];
    }
    zb[(cx + ch) * 18 + col + 1] = h;
    __syncthreads();
    float a0 = bb[ch], a1 = bb[16 + ch], a2 = bb[32 + ch], a3 = bb[48 + ch];
    for (int ic = 0; ic < cin; ++ic) {
      float z0 = zb[ic * 18 + col], z1 = zb[ic * 18 + col + 1], z2 = zb[ic * 18 + col + 2];
      const float* w0 = &wb[((0 * 16 + ch) * cin + ic) * 3];
      const float* w1 = &wb[((1 * 16 + ch) * cin + ic) * 3];
      const float* w2 = &wb[((2 * 16 + ch) * cin + ic) * 3];
      const float* w3 = &wb[((3 * 16 + ch) * cin + ic) * 3];
      a0 += z0 * w0[0] + z1 * w0[1] + z2 * w0[2];
      a1 += z0 * w1[0] + z1 * w1[1] + z2 * w1[2];
      a2 += z0 * w2[0] + z1 * w2[1] + z2 * w2[2];
      a3 += z0 * w3[0] + z1 * w3[1] + z2 * w3[2];
    }
    __syncthreads();
    c = sigm(a1) * c + sigm(a0) * tanhf(a2);   // i,f,g,o gate order
    h = sigm(a3) * tanhf(c);
    long idx = ((long)t * 16 + b) * 4096 + (long)r * 256 + ch * 16 + col;
    u16 hh = f2bf(h);
    hhi[idx] = hh;
    hlo[idx] = f2bf(h - bf2f(hh));
  }
}

// ---------------------------------------------------------------------------
// Transpose + split: W[4096][4096] fp32 (row k, col n) -> WT_hi/lo[n][k] bf16
// ---------------------------------------------------------------------------
__global__ __launch_bounds__(256) void k_tsplit(const float* __restrict__ W,
    u16* __restrict__ hi, u16* __restrict__ lo)
{
  __shared__ float tb[32][33];
  const int tn = blockIdx.x & 127, tk = blockIdx.x >> 7;
  const int n0 = tn * 32, k0 = tk * 32;
  const int lr = threadIdx.x >> 5, lc = threadIdx.x & 31;
  #pragma unroll
  for (int i = 0; i < 4; ++i)
    tb[lr + i * 8][lc] = W[(long)(k0 + lr + i * 8) * 4096 + n0 + lc];
  __syncthreads();
  #pragma unroll
  for (int i = 0; i < 4; ++i) {
    int n = lr + i * 8;
    float v = tb[lc][n];
    long idx = (long)(n0 + n) * 4096 + k0 + lc;
    u16 h = f2bf(v);
    hi[idx] = h;
    lo[idx] = f2bf(v - bf2f(h));
  }
}

// Elementwise split (no transpose) for wv
__global__ __launch_bounds__(256) void k_split(const float* __restrict__ W,
    u16* __restrict__ hi, u16* __restrict__ lo)
{
  long i = ((long)blockIdx.x * 256 + threadIdx.x) * 4;
  const float4 v = *(const float4*)&W[i];
  u16 h0 = f2bf(v.x), h1 = f2bf(v.y), h2 = f2bf(v.z), h3 = f2bf(v.w);
  ush4 hv = {h0, h1, h2, h3};
  ush4 lv = {f2bf(v.x - bf2f(h0)), f2bf(v.y - bf2f(h1)),
             f2bf(v.z - bf2f(h2)), f2bf(v.w - bf2f(h3))};
  *(ush4*)&hi[i] = hv;
  *(ush4*)&lo[i] = lv;
}

// ---------------------------------------------------------------------------
// Split-bf16 GEMM via global_load_lds + XOR-swizzled LDS.
// C[M][N] = A[M][4096] * B[N][4096]^T, A/B split hi/lo bf16.
// LDS pair tiles: PA/PB = [128 rows][8 slots x 16B]; slot s<4 = hi chunk s,
// s>=4 = lo chunk s-4; physical slot p = c ^ (row&7) (source pre-swizzled).
// grid.x = (M/128) << ntShift | nT;  grid.y = batch (strided A/B/C).
// mode 0: fp32 C.  mode 1: split hi/lo bf16 C.
// ---------------------------------------------------------------------------
__global__ __launch_bounds__(256) void k_gemm(
    const u16* __restrict__ Ahi, const u16* __restrict__ Alo, long lda, long aBS,
    const u16* __restrict__ Bhi, const u16* __restrict__ Blo, long ldb, long bBS,
    float* __restrict__ Cf, u16* __restrict__ Chi, u16* __restrict__ Clo,
    long ldc, long cBS, int ntShift, int mode)
{
  __shared__ __align__(16) u16 lds[16384];   // PA @0, PB @8192 (u16 units)
  const int tid = threadIdx.x;
  const int lane = tid & 63;
  const int wv = tid >> 6;
  const int bx = blockIdx.x;
  const int nT = bx & ((1 << ntShift) - 1);
  const int mT = bx >> ntShift;
  const long aOff = (long)blockIdx.y * aBS;
  const long bOff = (long)blockIdx.y * bBS;
  const long cOff = (long)blockIdx.y * cBS;
  const long aRow0 = (long)mT * 128;
  const long bRow0 = (long)nT * 128;

  // per-lane pre-swizzled global staging source (rule #21: swz both sides)
  const int l8 = lane >> 3;             // row-within-8 AND swizzle key
  const int cslot = (lane & 7) ^ l8;    // logical chunk this lane fetches
  const int ck = (cslot & 3) * 8;
  const u16* aSrc = ((cslot < 4) ? Ahi : Alo) + aOff + (aRow0 + wv * 32 + l8) * lda + ck;
  const u16* bSrc = ((cslot < 4) ? Bhi : Blo) + bOff + (bRow0 + wv * 32 + l8) * ldb + ck;
  u16* ldsA = lds + wv * 2048;          // wave wv stages rows wv*32..+31
  u16* ldsB = lds + 8192 + wv * 2048;

  const int r15 = lane & 15, kq = lane >> 4;
  const int s7 = r15 & 7;
  const int oHi = (kq ^ s7) * 8;        // swizzled u16 offset of hi chunk
  const int oLo = ((4 + kq) ^ s7) * 8;  // swizzled u16 offset of lo chunk
  const int aQ = (wv >> 1) * 64;        // waveM*64
  const int bQ = (wv & 1) * 64;         // waveN*64

  f32x4 acc[4][4] = {};

  for (int k0 = 0; k0 < 4096; k0 += 32) {
    const u16* sa = aSrc + k0;
    const u16* sb = bSrc + k0;
    gload16(sa,            ldsA);
    gload16(sa +  8 * lda, ldsA + 512);
    gload16(sa + 16 * lda, ldsA + 1024);
    gload16(sa + 24 * lda, ldsA + 1536);
    gload16(sb,            ldsB);
    gload16(sb +  8 * ldb, ldsB + 512);
    gload16(sb + 16 * ldb, ldsB + 1024);
    gload16(sb + 24 * ldb, ldsB + 1536);
    __syncthreads();                    // drains vmcnt(0): staged data ready
    short8v bh[4], bl[4];
    #pragma unroll
    for (int j = 0; j < 4; ++j) {
      int rb = 8192 + (bQ + j * 16 + r15) * 64;
      bh[j] = *(const short8v*)&lds[rb + oHi];
      bl[j] = *(const short8v*)&lds[rb + oLo];
    }
    #pragma unroll
    for (int i = 0; i < 4; ++i) {
      int ra = (aQ + i * 16 + r15) * 64;
      short8v ah = *(const short8v*)&lds[ra + oHi];
      short8v al = *(const short8v*)&lds[ra + oLo];
      #pragma unroll
      for (int j = 0; j < 4; ++j) {
        acc[i][j] = __builtin_amdgcn_mfma_f32_16x16x32_bf16(ah, bh[j], acc[i][j], 0, 0, 0);
        acc[i][j] = __builtin_amdgcn_mfma_f32_16x16x32_bf16(ah, bl[j], acc[i][j], 0, 0, 0);
        acc[i][j] = __builtin_amdgcn_mfma_f32_16x16x32_bf16(al, bh[j], acc[i][j], 0, 0, 0);
      }
    }
    __syncthreads();                    // all frag reads done before restage
  }
  // epilogue: D row=(lane>>4)*4+reg, col=lane&15 (measured m89 layout)
  const long row0 = aRow0 + aQ;
  const long col0 = bRow0 + bQ;
  #pragma unroll
  for (int i = 0; i < 4; ++i)
    #pragma unroll
    for (int j = 0; j < 4; ++j) {
      long rr = row0 + i * 16 + kq * 4;
      long cc = col0 + j * 16 + r15;
      #pragma unroll
      for (int g = 0; g < 4; ++g) {
        float v = acc[i][j][g];
        long idx = cOff + (rr + g) * ldc + cc;
        if (mode == 0) {
          Cf[idx] = v;
        } else {
          u16 h = f2bf(v);
          Chi[idx] = h;
          Clo[idx] = f2bf(v - bf2f(h));
        }
      }
    }
}

// Softmax over strictly-past scores -> Wx[t][b][t']  (zero row at t=0)
__global__ __launch_bounds__(256) void k_softmax(const float* __restrict__ S,
    float* __restrict__ Wx)
{
  const int wv = threadIdx.x >> 6, lane = threadIdx.x & 63;
  const int idx = blockIdx.x * 4 + wv;        // = b*128 + t
  const int b = idx >> 7, t = idx & 127;
  const float* row = &S[(long)idx * 128];
  float v0 = (lane < t) ? row[lane] * 0.015625f : -1e30f;
  float v1 = (lane + 64 < t) ? row[lane + 64] * 0.015625f : -1e30f;
  float m = fmaxf(v0, v1);
  #pragma unroll
  for (int off = 32; off; off >>= 1) m = fmaxf(m, __shfl_xor(m, off));
  float e0 = (lane < t) ? expf(v0 - m) : 0.f;
  float e1 = (lane + 64 < t) ? expf(v1 - m) : 0.f;
  float s = e0 + e1;
  #pragma unroll
  for (int off = 32; off; off >>= 1) s += __shfl_xor(s, off);
  float inv = 1.f / fmaxf(s, 1e-9f);
  float* wr = &Wx[((long)t * 16 + b) * 128];
  wr[lane] = e0 * inv;
  wr[lane + 64] = e1 * inv;
}

// out_0 = tanh(ho_0); writes f32 dest + split-bf16 step buffer
__global__ __launch_bounds__(256) void k_prologue(const float* __restrict__ HO,
    float* __restrict__ fdest, int dmode, u16* __restrict__ ohi, u16* __restrict__ olo)
{
  int i = blockIdx.x * 256 + threadIdx.x;   // b*4096 + d, 65536 total
  float v = tanhf(HO[i]);
  u16 h = f2bf(v);
  ohi[i] = h;
  olo[i] = f2bf(v - bf2f(h));
  if (dmode == 0) fdest[i] = v;
  else {
    int b = i >> 12, d = i & 4095;
    fdest[(long)b * 128 * 4096 + d] = v;    // d_out[b][0][d]
  }
}

// ---------------------------------------------------------------------------
// Sequential step t: vo_t = out_t @ Wvo, direct-from-global MFMA fragments
// (no LDS staging, no K-loop barriers). 512 threads: 8 waves split K 8-way.
// Then out_{t+1} = tanh(ho_{t+1} + sum_{t'<=t} w[t+1][b][t'] * vo_{t'}).
// ---------------------------------------------------------------------------
__global__ __launch_bounds__(512) void k_step(int t,
    const u16* __restrict__ Wvh, const u16* __restrict__ Wvl,
    const float* __restrict__ Wx, const float* __restrict__ HO,
    float* __restrict__ VO,
    const u16* __restrict__ ihi, const u16* __restrict__ ilo,
    u16* __restrict__ ohi, u16* __restrict__ olo,
    float* __restrict__ fdest, int dmode)
{
  __shared__ float vo_w[8][256];
  __shared__ float vsum[256];
  __shared__ float pctx[2][256];
  const int tid = threadIdx.x;
  const int lane = tid & 63, wv = tid >> 6;
  const int n0 = blockIdx.x * 16;
  const int r15 = lane & 15, kq = lane >> 4;
  const long kb = (long)wv * 512 + kq * 8;   // this wave's K slice
  const u16* pAh = ihi + (long)r15 * 4096 + kb;
  const u16* pAl = ilo + (long)r15 * 4096 + kb;
  const u16* pBh = Wvh + (long)(n0 + r15) * 4096 + kb;
  const u16* pBl = Wvl + (long)(n0 + r15) * 4096 + kb;
  f32x4 acc = {0.f, 0.f, 0.f, 0.f};
  short8v a0h = *(const short8v*)pAh, a0l = *(const short8v*)pAl;
  short8v b0h = *(const short8v*)pBh, b0l = *(const short8v*)pBl;
  #pragma unroll
  for (int c = 0; c < 16; c += 2) {
    short8v a1h, a1l, b1h, b1l;
    {
      int o = (c + 1) * 32;
      a1h = *(const short8v*)(pAh + o); a1l = *(const short8v*)(pAl + o);
      b1h = *(const short8v*)(pBh + o); b1l = *(const short8v*)(pBl + o);
    }
    acc = __builtin_amdgcn_mfma_f32_16x16x32_bf16(a0h, b0h, acc, 0, 0, 0);
    acc = __builtin_amdgcn_mfma_f32_16x16x32_bf16(a0h, b0l, acc, 0, 0, 0);
    acc = __builtin_amdgcn_mfma_f32_16x16x32_bf16(a0l, b0h, acc, 0, 0, 0);
    if (c + 2 < 16) {
      int o = (c + 2) * 32;
      a0h = *(const short8v*)(pAh + o); a0l = *(const short8v*)(pAl + o);
      b0h = *(const short8v*)(pBh + o); b0l = *(const short8v*)(pBl + o);
    }
    acc = __builtin_amdgcn_mfma_f32_16x16x32_bf16(a1h, b1h, acc, 0, 0, 0);
    acc = __builtin_amdgcn_mfma_f32_16x16x32_bf16(a1h, b1l, acc, 0, 0, 0);
    acc = __builtin_amdgcn_mfma_f32_16x16x32_bf16(a1l, b1h, acc, 0, 0, 0);
  }
  #pragma unroll
  for (int g = 0; g < 4; ++g)
    vo_w[wv][(kq * 4 + g) * 16 + r15] = acc[g];   // row=batch, col=out col
  __syncthreads();
  if (tid < 256) {
    float v = vo_w[0][tid] + vo_w[1][tid] + vo_w[2][tid] + vo_w[3][tid]
            + vo_w[4][tid] + vo_w[5][tid] + vo_w[6][tid] + vo_w[7][tid];
    vsum[tid] = v;
    const int b = tid >> 4, col = tid & 15;
    VO[((long)t * 16 + b) * 4096 + n0 + col] = v;
  }
  __syncthreads();
  if (t < 127) {
    const int p = tid >> 8, id = tid & 255;
    const int b = id >> 4, col = id & 15;
    const float* wrow = &Wx[((long)(t + 1) * 16 + b) * 128];
    const float* vcol = &VO[(long)b * 4096 + n0 + col];
    float ctx = 0.f;
    for (int tp = p; tp < t; tp += 2)
      ctx += wrow[tp] * vcol[(long)tp * 65536];
    pctx[p][id] = ctx;
    __syncthreads();
    if (tid < 256) {
      float o = tanhf(HO[((long)(t + 1) * 16 + b) * 4096 + n0 + col]
                      + pctx[0][id] + pctx[1][id] + wrow[t] * vsum[id]);
      long oi = (long)b * 4096 + n0 + col;
      u16 hh = f2bf(o);
      ohi[oi] = hh;
      olo[oi] = f2bf(o - bf2f(hh));
      if (dmode == 0) fdest[((long)(t + 1) * 16 + b) * 4096 + n0 + col] = o;
      else            fdest[((long)b * 128 + (t + 1)) * 4096 + n0 + col] = o;
    }
  }
}

// ---------------------------------------------------------------------------
extern "C" void kernel_launch(void* const* d_in, const int* in_sizes, int n_in,
                              void* d_out, int out_size, void* d_ws, size_t ws_size,
                              hipStream_t stream)
{
  (void)in_sizes; (void)n_in; (void)out_size;
  if (ws_size < 472383488UL) return;  // need ~451 MiB scratch
  char* ws = (char*)d_ws;
  u16* WT_hi = (u16*)(ws + 0UL);
  u16* WT_lo = (u16*)(ws + 33554432UL);
  u16* WV_hi = (u16*)(ws + 67108864UL);
  u16* WV_lo = (u16*)(ws + 100663296UL);
  u16* Wvo_hi[2] = {(u16*)(ws + 134217728UL), (u16*)(ws + 201326592UL)};
  u16* Wvo_lo[2] = {(u16*)(ws + 167772160UL), (u16*)(ws + 234881024UL)};
  u16* Hs_hi = (u16*)(ws + 268435456UL);
  u16* Hs_lo = (u16*)(ws + 285212672UL);
  u16* Qh   = (u16*)(ws + 301989888UL);
  u16* Ql   = (u16*)(ws + 318767104UL);
  u16* Kh   = (u16*)(ws + 335544320UL);
  u16* Kl   = (u16*)(ws + 352321536UL);
  float* HOb  = (float*)(ws + 369098752UL);
  float* Sb   = (float*)(ws + 402653184UL);
  float* Wmx  = (float*)(ws + 403701760UL);
  float* VOb  = (float*)(ws + 404750336UL);
  float* OUT0 = (float*)(ws + 438304768UL);
  u16* obh[2] = {(u16*)(ws + 471859200UL), (u16*)(ws + 472121344UL)};
  u16* obl[2] = {(u16*)(ws + 471990272UL), (u16*)(ws + 472252416UL)};
  float* dout = (float*)d_out;
  const float* x_flat = (const float*)d_in[0];

  for (int l = 0; l < 2; ++l) {
    const float* cw = (const float*)d_in[1 + l * 6];
    const float* cb = (const float*)d_in[2 + l * 6];
    const float* wq = (const float*)d_in[3 + l * 6];
    const float* wk = (const float*)d_in[4 + l * 6];
    const float* wv = (const float*)d_in[5 + l * 6];
    const float* wo = (const float*)d_in[6 + l * 6];
    const int cin = (l == 0) ? 17 : 32;

    // Phase A: ConvLSTM recurrence -> split h_vec rows
    hipLaunchKernelGGL(k_conv, dim3(256), dim3(256), 0, stream,
        cin, l, (l == 0) ? x_flat : OUT0, cw, cb, Hs_hi, Hs_lo);

    // Phase B: batched GEMMs (Q, K split out; HO fp32) + composite Wvo
    hipLaunchKernelGGL(k_tsplit, dim3(16384), dim3(256), 0, stream, wq, WT_hi, WT_lo);
    hipLaunchKernelGGL(k_gemm, dim3(512, 1), dim3(256), 0, stream,
        Hs_hi, Hs_lo, 4096L, 0L, WT_hi, WT_lo, 4096L, 0L,
        (float*)nullptr, Qh, Ql, 4096L, 0L, 5, 1);
    hipLaunchKernelGGL(k_tsplit, dim3(16384), dim3(256), 0, stream, wk, WT_hi, WT_lo);
    hipLaunchKernelGGL(k_gemm, dim3(512, 1), dim3(256), 0, stream,
        Hs_hi, Hs_lo, 4096L, 0L, WT_hi, WT_lo, 4096L, 0L,
        (float*)nullptr, Kh, Kl, 4096L, 0L, 5, 1);
    hipLaunchKernelGGL(k_tsplit, dim3(16384), dim3(256), 0, stream, wo, WT_hi, WT_lo);
    hipLaunchKernelGGL(k_gemm, dim3(512, 1), dim3(256), 0, stream,
        Hs_hi, Hs_lo, 4096L, 0L, WT_hi, WT_lo, 4096L, 0L,
        HOb, (u16*)nullptr, (u16*)nullptr, 4096L, 0L, 5, 0);
    hipLaunchKernelGGL(k_tsplit, dim3(16384), dim3(256), 0, stream,
        wo + 16777216UL, WT_hi, WT_lo);                       // wo_c^T
    hipLaunchKernelGGL(k_split, dim3(16384), dim3(256), 0, stream, wv, WV_hi, WV_lo);
    // WvoT[n][k] = sum_m wo_c[m][n] * wv[k][m]
    hipLaunchKernelGGL(k_gemm, dim3(1024, 1), dim3(256), 0, stream,
        WT_hi, WT_lo, 4096L, 0L, WV_hi, WV_lo, 4096L, 0L,
        (float*)nullptr, Wvo_hi[l], Wvo_lo[l], 4096L, 0L, 5, 1);

    // Scores via batched MFMA GEMM: S[b][t][t'] = Q[t,b,:]·K[t',b,:]
    hipLaunchKernelGGL(k_gemm, dim3(1, 16), dim3(256), 0, stream,
        Qh, Ql, 65536L, 4096L, Kh, Kl, 65536L, 4096L,
        Sb, (u16*)nullptr, (u16*)nullptr, 128L, 16384L, 0, 0);
    hipLaunchKernelGGL(k_softmax, dim3(512), dim3(256), 0, stream, Sb, Wmx);

    // Phase C: sequential attention/value recurrence
    hipLaunchKernelGGL(k_prologue, dim3(256), dim3(256), 0, stream,
        HOb, (l == 0) ? OUT0 : dout, l, obh[0], obl[0]);
    for (int t = 0; t < 127; ++t) {
      hipLaunchKernelGGL(k_step, dim3(256), dim3(512), 0, stream,
          t, Wvo_hi[l], Wvo_lo[l], Wmx, HOb, VOb,
          obh[t & 1], obl[t & 1], obh[(t + 1) & 1], obl[(t + 1) & 1],
          (l == 0) ? OUT0 : dout, l);
    }
  }
}

// Round 3
// 9998.720 us; speedup vs baseline: 1.0188x; 1.0188x over previous
//
#include <hip/hip_runtime.h>

typedef unsigned short u16;
typedef unsigned int u32;
typedef __attribute__((ext_vector_type(8))) short short8v;   // 8 bf16 (4 VGPR) MFMA frag
typedef __attribute__((ext_vector_type(4))) float f32x4;     // MFMA acc
typedef __attribute__((ext_vector_type(8))) u16 ush8;
typedef __attribute__((ext_vector_type(4))) u16 ush4;

__device__ __forceinline__ u16 f2bf(float x) {               // RNE f32->bf16
  u32 u = __builtin_bit_cast(u32, x);
  return (u16)((u + 0x7FFFu + ((u >> 16) & 1u)) >> 16);
}
__device__ __forceinline__ float bf2f(u16 h) {
  u32 u = ((u32)h) << 16;
  return __builtin_bit_cast(float, u);
}
__device__ __forceinline__ float sigm(float x) { return 1.f / (1.f + expf(-x)); }

typedef const __attribute__((address_space(1))) void gv_t;
typedef __attribute__((address_space(3))) void lv_t;
__device__ __forceinline__ void gload16(const void* g, void* l) {
  __builtin_amdgcn_global_load_lds((gv_t*)g, (lv_t*)l, 16, 0, 0);
}

// ---------------------------------------------------------------------------
// ConvLSTM recurrence: one WG per (b, row). Computes h for all t, stores
// split-bf16 h_vec rows [t*16+b][4096].  d = r*256 + ch*16 + col.
// ---------------------------------------------------------------------------
__global__ __launch_bounds__(256) void k_conv(int cin, int xmode,
    const float* __restrict__ xin, const float* __restrict__ cw,
    const float* __restrict__ cb, u16* __restrict__ hhi, u16* __restrict__ hlo)
{
  __shared__ float zb[32 * 18];        // cin x (16+2 pad)
  __shared__ float wb[64 * 32 * 3];
  __shared__ float bb[64];
  const int tid = threadIdx.x;
  const int b = blockIdx.x >> 4, r = blockIdx.x & 15;
  const int ch = tid >> 4, col = tid & 15;
  const int cx = cin - 16;
  for (int i = tid; i < 64 * cin * 3; i += 256) wb[i] = cw[i];
  if (tid < 64) bb[tid] = cb[tid];
  for (int i = tid; i < cin * 18; i += 256) zb[i] = 0.f;  // includes pad cols
  __syncthreads();
  float h = 0.f, c = 0.f;
  for (int t = 0; t < 128; ++t) {
    if (xmode == 0) {
      if (ch == 0) zb[col + 1] = xin[((long)b * 128 + t) * 256 + r * 16 + col];
    } else {
      zb[ch * 18 + col + 1] = xin[((long)t * 16 + b) * 4096 + r * 256 + ch * 16 + col];
    }
    zb[(cx + ch) * 18 + col + 1] = h;
    __syncthreads();
    float a0 = bb[ch], a1 = bb[16 + ch], a2 = bb[32 + ch], a3 = bb[48 + ch];
    for (int ic = 0; ic < cin; ++ic) {
      float z0 = zb[ic * 18 + col], z1 = zb[ic * 18 + col + 1], z2 = zb[ic * 18 + col + 2];
      const float* w0 = &wb[((0 * 16 + ch) * cin + ic) * 3];
      const float* w1 = &wb[((1 * 16 + ch) * cin + ic) * 3];
      const float* w2 = &wb[((2 * 16 + ch) * cin + ic) * 3];
      const float* w3 = &wb[((3 * 16 + ch) * cin + ic) * 3];
      a0 += z0 * w0[0] + z1 * w0[1] + z2 * w0[2];
      a1 += z0 * w1[0] + z1 * w1[1] + z2 * w1[2];
      a2 += z0 * w2[0] + z1 * w2[1] + z2 * w2[2];
      a3 += z0 * w3[0] + z1 * w3[1] + z2 * w3[2];
    }
    __syncthreads();
    c = sigm(a1) * c + sigm(a0) * tanhf(a2);   // i,f,g,o gate order
    h = sigm(a3) * tanhf(c);
    long idx = ((long)t * 16 + b) * 4096 + (long)r * 256 + ch * 16 + col;
    u16 hh = f2bf(h);
    hhi[idx] = hh;
    hlo[idx] = f2bf(h - bf2f(hh));
  }
}

// ---------------------------------------------------------------------------
// Transpose + split: W[4096][4096] fp32 (row k, col n) -> WT_hi/lo[n][k] bf16
// ---------------------------------------------------------------------------
__global__ __launch_bounds__(256) void k_tsplit(const float* __restrict__ W,
    u16* __restrict__ hi, u16* __restrict__ lo)
{
  __shared__ float tb[32][33];
  const int tn = blockIdx.x & 127, tk = blockIdx.x >> 7;
  const int n0 = tn * 32, k0 = tk * 32;
  const int lr = threadIdx.x >> 5, lc = threadIdx.x & 31;
  #pragma unroll
  for (int i = 0; i < 4; ++i)
    tb[lr + i * 8][lc] = W[(long)(k0 + lr + i * 8) * 4096 + n0 + lc];
  __syncthreads();
  #pragma unroll
  for (int i = 0; i < 4; ++i) {
    int n = lr + i * 8;
    float v = tb[lc][n];
    long idx = (long)(n0 + n) * 4096 + k0 + lc;
    u16 h = f2bf(v);
    hi[idx] = h;
    lo[idx] = f2bf(v - bf2f(h));
  }
}

// Elementwise split (no transpose) for wv
__global__ __launch_bounds__(256) void k_split(const float* __restrict__ W,
    u16* __restrict__ hi, u16* __restrict__ lo)
{
  long i = ((long)blockIdx.x * 256 + threadIdx.x) * 4;
  const float4 v = *(const float4*)&W[i];
  u16 h0 = f2bf(v.x), h1 = f2bf(v.y), h2 = f2bf(v.z), h3 = f2bf(v.w);
  ush4 hv = {h0, h1, h2, h3};
  ush4 lv = {f2bf(v.x - bf2f(h0)), f2bf(v.y - bf2f(h1)),
             f2bf(v.z - bf2f(h2)), f2bf(v.w - bf2f(h3))};
  *(ush4*)&hi[i] = hv;
  *(ush4*)&lo[i] = lv;
}

// ---------------------------------------------------------------------------
// Split-bf16 GEMM via global_load_lds + XOR-swizzled, DOUBLE-BUFFERED LDS.
// C[M][N] = A[M][4096] * B[N][4096]^T, A/B split hi/lo bf16. K = 4096.
// Per K-step: STAGE(next buf) -> ds_read+MFMA(cur) -> one __syncthreads().
// grid.x = mT * nTc + nT;  grid.y = batch (strided A/B/C).
// mode 0: fp32 C.  mode 1: split hi/lo bf16 C.
// ---------------------------------------------------------------------------
__global__ __launch_bounds__(256) void k_gemm(
    const u16* __restrict__ Ahi, const u16* __restrict__ Alo, long lda, long aBS,
    const u16* __restrict__ Bhi, const u16* __restrict__ Blo, long ldb, long bBS,
    float* __restrict__ Cf, u16* __restrict__ Chi, u16* __restrict__ Clo,
    long ldc, long cBS, int nTc, int mode)
{
  __shared__ __align__(16) u16 lds[2][16384];   // per buf: PA @0, PB @8192
  const int tid = threadIdx.x;
  const int lane = tid & 63;
  const int wv = tid >> 6;
  const int bx = blockIdx.x;
  const int nT = bx % nTc;
  const int mT = bx / nTc;
  const long aOff = (long)blockIdx.y * aBS;
  const long bOff = (long)blockIdx.y * bBS;
  const long cOff = (long)blockIdx.y * cBS;
  const long aRow0 = (long)mT * 128;
  const long bRow0 = (long)nT * 128;

  // per-lane pre-swizzled global staging source (rule #21: swz both sides)
  const int l8 = lane >> 3;             // row-within-8 AND swizzle key
  const int cslot = (lane & 7) ^ l8;    // logical chunk this lane fetches
  const int ck = (cslot & 3) * 8;
  const u16* aSrc = ((cslot < 4) ? Ahi : Alo) + aOff + (aRow0 + wv * 32 + l8) * lda + ck;
  const u16* bSrc = ((cslot < 4) ? Bhi : Blo) + bOff + (bRow0 + wv * 32 + l8) * ldb + ck;
  const int ldsAo = wv * 2048;          // wave wv stages rows wv*32..+31
  const int ldsBo = 8192 + wv * 2048;

  const int r15 = lane & 15, kq = lane >> 4;
  const int s7 = r15 & 7;
  const int oHi = (kq ^ s7) * 8;        // swizzled u16 offset of hi chunk
  const int oLo = ((4 + kq) ^ s7) * 8;  // swizzled u16 offset of lo chunk
  const int aQ = (wv >> 1) * 64;        // waveM*64
  const int bQ = (wv & 1) * 64;         // waveN*64

  f32x4 acc[4][4] = {};

#define STAGE(buf, kofs)                                                     \
  {                                                                          \
    const u16* sa = aSrc + (kofs);                                           \
    const u16* sb = bSrc + (kofs);                                           \
    u16* la = &lds[buf][ldsAo];                                              \
    u16* lb = &lds[buf][ldsBo];                                              \
    gload16(sa,            la);        gload16(sa +  8 * lda, la + 512);     \
    gload16(sa + 16 * lda, la + 1024); gload16(sa + 24 * lda, la + 1536);    \
    gload16(sb,            lb);        gload16(sb +  8 * ldb, lb + 512);     \
    gload16(sb + 16 * ldb, lb + 1024); gload16(sb + 24 * ldb, lb + 1536);    \
  }

  STAGE(0, 0)
  __syncthreads();                      // vmcnt(0) drained: buf0 ready
  int cur = 0;
  for (int k0 = 0; k0 < 4096; k0 += 32) {
    if (k0 + 32 < 4096) STAGE(cur ^ 1, k0 + 32)   // flies during MFMA phase
    const u16* L = &lds[cur][0];
    short8v bh[4], bl[4];
    #pragma unroll
    for (int j = 0; j < 4; ++j) {
      int rb = 8192 + (bQ + j * 16 + r15) * 64;
      bh[j] = *(const short8v*)&L[rb + oHi];
      bl[j] = *(const short8v*)&L[rb + oLo];
    }
    #pragma unroll
    for (int i = 0; i < 4; ++i) {
      int ra = (aQ + i * 16 + r15) * 64;
      short8v ah = *(const short8v*)&L[ra + oHi];
      short8v al = *(const short8v*)&L[ra + oLo];
      #pragma unroll
      for (int j = 0; j < 4; ++j) {
        acc[i][j] = __builtin_amdgcn_mfma_f32_16x16x32_bf16(ah, bh[j], acc[i][j], 0, 0, 0);
        acc[i][j] = __builtin_amdgcn_mfma_f32_16x16x32_bf16(ah, bl[j], acc[i][j], 0, 0, 0);
        acc[i][j] = __builtin_amdgcn_mfma_f32_16x16x32_bf16(al, bh[j], acc[i][j], 0, 0, 0);
      }
    }
    __syncthreads();   // next buf staged + all reads of cur done
    cur ^= 1;
  }
#undef STAGE
  // epilogue: D row=(lane>>4)*4+reg, col=lane&15 (measured m89 layout)
  const long row0 = aRow0 + aQ;
  const long col0 = bRow0 + bQ;
  #pragma unroll
  for (int i = 0; i < 4; ++i)
    #pragma unroll
    for (int j = 0; j < 4; ++j) {
      long rr = row0 + i * 16 + kq * 4;
      long cc = col0 + j * 16 + r15;
      #pragma unroll
      for (int g = 0; g < 4; ++g) {
        float v = acc[i][j][g];
        long idx = cOff + (rr + g) * ldc + cc;
        if (mode == 0) {
          Cf[idx] = v;
        } else {
          u16 h = f2bf(v);
          Chi[idx] = h;
          Clo[idx] = f2bf(v - bf2f(h));
        }
      }
    }
}

// Softmax over strictly-past scores -> Wx[t][b][t']  (zero row at t=0)
__global__ __launch_bounds__(256) void k_softmax(const float* __restrict__ S,
    float* __restrict__ Wx)
{
  const int wv = threadIdx.x >> 6, lane = threadIdx.x & 63;
  const int idx = blockIdx.x * 4 + wv;        // = b*128 + t
  const int b = idx >> 7, t = idx & 127;
  const float* row = &S[(long)idx * 128];
  float v0 = (lane < t) ? row[lane] * 0.015625f : -1e30f;
  float v1 = (lane + 64 < t) ? row[lane + 64] * 0.015625f : -1e30f;
  float m = fmaxf(v0, v1);
  #pragma unroll
  for (int off = 32; off; off >>= 1) m = fmaxf(m, __shfl_xor(m, off));
  float e0 = (lane < t) ? expf(v0 - m) : 0.f;
  float e1 = (lane + 64 < t) ? expf(v1 - m) : 0.f;
  float s = e0 + e1;
  #pragma unroll
  for (int off = 32; off; off >>= 1) s += __shfl_xor(s, off);
  float inv = 1.f / fmaxf(s, 1e-9f);
  float* wr = &Wx[((long)t * 16 + b) * 128];
  wr[lane] = e0 * inv;
  wr[lane + 64] = e1 * inv;
}

// out_0 = tanh(ho_0); ho given split-bf16 at stride 12288 (QKO col 8192+)
__global__ __launch_bounds__(256) void k_prologue(
    const u16* __restrict__ hoh, const u16* __restrict__ hol,
    float* __restrict__ fdest, int dmode, u16* __restrict__ ohi, u16* __restrict__ olo)
{
  int i = blockIdx.x * 256 + threadIdx.x;   // b*4096 + d, 65536 total
  int b = i >> 12, d = i & 4095;
  long hix = (long)b * 12288 + d;
  float v = tanhf(bf2f(hoh[hix]) + bf2f(hol[hix]));
  u16 h = f2bf(v);
  ohi[i] = h;
  olo[i] = f2bf(v - bf2f(h));
  if (dmode == 0) fdest[i] = v;
  else fdest[(long)b * 128 * 4096 + d] = v;    // d_out[b][0][d]
}

// ---------------------------------------------------------------------------
// Sequential step t: vo_t = out_t @ Wvo, direct-from-global MFMA fragments,
// 2-deep BOUNDED register pipeline (no LDS staging, no K-loop barriers).
// 512 threads: 8 waves split K 8-way (512 elems = 16 chunks of 32 each).
// Then out_{t+1} = tanh(ho_{t+1} + sum_{t'<=t} w[t+1][b][t'] * vo_{t'}).
// ---------------------------------------------------------------------------
__global__ __launch_bounds__(512) void k_step(int t,
    const u16* __restrict__ Wvh, const u16* __restrict__ Wvl,
    const float* __restrict__ Wx,
    const u16* __restrict__ hoh, const u16* __restrict__ hol,
    float* __restrict__ VO,
    const u16* __restrict__ ihi, const u16* __restrict__ ilo,
    u16* __restrict__ ohi, u16* __restrict__ olo,
    float* __restrict__ fdest, int dmode)
{
  __shared__ float vo_w[8][256];
  __shared__ float vsum[256];
  __shared__ float pctx[2][256];
  const int tid = threadIdx.x;
  const int lane = tid & 63, wv = tid >> 6;
  const int n0 = blockIdx.x * 16;
  const int r15 = lane & 15, kq = lane >> 4;
  const long kb = (long)wv * 512 + kq * 8;   // this wave's K slice
  const u16* pAh = ihi + (long)r15 * 4096 + kb;
  const u16* pAl = ilo + (long)r15 * 4096 + kb;
  const u16* pBh = Wvh + (long)(n0 + r15) * 4096 + kb;
  const u16* pBl = Wvl + (long)(n0 + r15) * 4096 + kb;
  f32x4 acc = {0.f, 0.f, 0.f, 0.f};

#define MF3(Ah, Al, Bh, Bl)                                                  \
  acc = __builtin_amdgcn_mfma_f32_16x16x32_bf16(Ah, Bh, acc, 0, 0, 0);       \
  acc = __builtin_amdgcn_mfma_f32_16x16x32_bf16(Ah, Bl, acc, 0, 0, 0);       \
  acc = __builtin_amdgcn_mfma_f32_16x16x32_bf16(Al, Bh, acc, 0, 0, 0);

  short8v A0h = *(const short8v*)pAh,        A0l = *(const short8v*)pAl;
  short8v B0h = *(const short8v*)pBh,        B0l = *(const short8v*)pBl;
  short8v A1h = *(const short8v*)(pAh + 32), A1l = *(const short8v*)(pAl + 32);
  short8v B1h = *(const short8v*)(pBh + 32), B1l = *(const short8v*)(pBl + 32);
  #pragma unroll 1
  for (int c = 0; c < 14; c += 2) {          // compute c,c+1; prefetch c+2,c+3
    const int o2 = (c + 2) * 32, o3 = (c + 3) * 32;
    short8v nAh = *(const short8v*)(pAh + o2), nAl = *(const short8v*)(pAl + o2);
    short8v nBh = *(const short8v*)(pBh + o2), nBl = *(const short8v*)(pBl + o2);
    MF3(A0h, A0l, B0h, B0l)
    short8v mAh = *(const short8v*)(pAh + o3), mAl = *(const short8v*)(pAl + o3);
    short8v mBh = *(const short8v*)(pBh + o3), mBl = *(const short8v*)(pBl + o3);
    MF3(A1h, A1l, B1h, B1l)
    A0h = nAh; A0l = nAl; B0h = nBh; B0l = nBl;
    A1h = mAh; A1l = mAl; B1h = mBh; B1l = mBl;
  }
  MF3(A0h, A0l, B0h, B0l)                    // chunk 14
  MF3(A1h, A1l, B1h, B1l)                    // chunk 15
#undef MF3

  #pragma unroll
  for (int g = 0; g < 4; ++g)
    vo_w[wv][(kq * 4 + g) * 16 + r15] = acc[g];   // row=batch, col=out col
  __syncthreads();
  if (tid < 256) {
    float v = vo_w[0][tid] + vo_w[1][tid] + vo_w[2][tid] + vo_w[3][tid]
            + vo_w[4][tid] + vo_w[5][tid] + vo_w[6][tid] + vo_w[7][tid];
    vsum[tid] = v;
    const int b = tid >> 4, col = tid & 15;
    VO[((long)t * 16 + b) * 4096 + n0 + col] = v;
  }
  __syncthreads();
  if (t < 127) {
    const int p = tid >> 8, id = tid & 255;
    const int b = id >> 4, col = id & 15;
    const float* wrow = &Wx[((long)(t + 1) * 16 + b) * 128];
    const float* vcol = &VO[(long)b * 4096 + n0 + col];
    float ctx = 0.f;
    for (int tp = p; tp < t; tp += 2)
      ctx += wrow[tp] * vcol[(long)tp * 65536];
    pctx[p][id] = ctx;
    __syncthreads();
    if (tid < 256) {
      long hix = ((long)(t + 1) * 16 + b) * 12288 + n0 + col;
      float ho = bf2f(hoh[hix]) + bf2f(hol[hix]);
      float o = tanhf(ho + pctx[0][id] + pctx[1][id] + wrow[t] * vsum[id]);
      long oi = (long)b * 4096 + n0 + col;
      u16 hh = f2bf(o);
      ohi[oi] = hh;
      olo[oi] = f2bf(o - bf2f(hh));
      if (dmode == 0) fdest[((long)(t + 1) * 16 + b) * 4096 + n0 + col] = o;
      else            fdest[((long)b * 128 + (t + 1)) * 4096 + n0 + col] = o;
    }
  }
}

// ---------------------------------------------------------------------------
extern "C" void kernel_launch(void* const* d_in, const int* in_sizes, int n_in,
                              void* d_out, int out_size, void* d_ws, size_t ws_size,
                              hipStream_t stream)
{
  (void)in_sizes; (void)n_in; (void)out_size;
  if (ws_size < 472383488UL) return;  // need ~451 MiB scratch
  char* ws = (char*)d_ws;
  // Stacked B^T for the fused Q|K|HO GEMM: [12288][4096] split bf16
  u16* WT_hi = (u16*)(ws + 0UL);               // 96 MB
  u16* WT_lo = (u16*)(ws + 100663296UL);       // 96 MB
  // WV reuses dead WT rows 4096..8191 at Wvo-GEMM time
  u16* WV_hi = (u16*)(ws + 33554432UL);
  u16* WV_lo = (u16*)(ws + 134217728UL);
  u16* QKOh  = (u16*)(ws + 201326592UL);       // [2048][12288] hi (48 MB)
  u16* QKOl  = (u16*)(ws + 251658240UL);       // lo (48 MB)
  u16* Wvo_hi = (u16*)(ws + 301989888UL);      // 32 MB (reused per layer)
  u16* Wvo_lo = (u16*)(ws + 335544320UL);      // 32 MB
  u16* Hs_hi = (u16*)(ws + 369098752UL);       // 16 MB
  u16* Hs_lo = (u16*)(ws + 385875968UL);
  float* Sb   = (float*)(ws + 402653184UL);
  float* Wmx  = (float*)(ws + 403701760UL);
  float* VOb  = (float*)(ws + 404750336UL);
  float* OUT0 = (float*)(ws + 438304768UL);
  u16* obh[2] = {(u16*)(ws + 471859200UL), (u16*)(ws + 472121344UL)};
  u16* obl[2] = {(u16*)(ws + 471990272UL), (u16*)(ws + 472252416UL)};
  float* dout = (float*)d_out;
  const float* x_flat = (const float*)d_in[0];

  for (int l = 0; l < 2; ++l) {
    const float* cw = (const float*)d_in[1 + l * 6];
    const float* cb = (const float*)d_in[2 + l * 6];
    const float* wq = (const float*)d_in[3 + l * 6];
    const float* wk = (const float*)d_in[4 + l * 6];
    const float* wv = (const float*)d_in[5 + l * 6];
    const float* wo = (const float*)d_in[6 + l * 6];
    const int cin = (l == 0) ? 17 : 32;

    // Phase A: ConvLSTM recurrence -> split h_vec rows
    hipLaunchKernelGGL(k_conv, dim3(256), dim3(256), 0, stream,
        cin, l, (l == 0) ? x_flat : OUT0, cw, cb, Hs_hi, Hs_lo);

    // Phase B1: stack wq^T | wk^T | wo_h^T into WT, then ONE fused GEMM
    hipLaunchKernelGGL(k_tsplit, dim3(16384), dim3(256), 0, stream,
        wq, WT_hi, WT_lo);
    hipLaunchKernelGGL(k_tsplit, dim3(16384), dim3(256), 0, stream,
        wk, WT_hi + 16777216UL, WT_lo + 16777216UL);
    hipLaunchKernelGGL(k_tsplit, dim3(16384), dim3(256), 0, stream,
        wo, WT_hi + 33554432UL, WT_lo + 33554432UL);
    hipLaunchKernelGGL(k_gemm, dim3(16 * 96, 1), dim3(256), 0, stream,
        Hs_hi, Hs_lo, 4096L, 0L, WT_hi, WT_lo, 4096L, 0L,
        (float*)nullptr, QKOh, QKOl, 12288L, 0L, 96, 1);

    // Phase B2: composite Wvo^T = (wv @ wo_c)^T
    hipLaunchKernelGGL(k_tsplit, dim3(16384), dim3(256), 0, stream,
        wo + 16777216UL, WT_hi, WT_lo);                       // wo_c^T
    hipLaunchKernelGGL(k_split, dim3(16384), dim3(256), 0, stream, wv, WV_hi, WV_lo);
    hipLaunchKernelGGL(k_gemm, dim3(32 * 32, 1), dim3(256), 0, stream,
        WT_hi, WT_lo, 4096L, 0L, WV_hi, WV_lo, 4096L, 0L,
        (float*)nullptr, Wvo_hi, Wvo_lo, 4096L, 0L, 32, 1);

    // Scores via batched MFMA GEMM: S[b][t][t'] = Q[t,b,:]·K[t',b,:]
    hipLaunchKernelGGL(k_gemm, dim3(1, 16), dim3(256), 0, stream,
        QKOh, QKOl, 196608L, 12288L, QKOh + 4096, QKOl + 4096, 196608L, 12288L,
        Sb, (u16*)nullptr, (u16*)nullptr, 128L, 16384L, 1, 0);
    hipLaunchKernelGGL(k_softmax, dim3(512), dim3(256), 0, stream, Sb, Wmx);

    // Phase C: sequential attention/value recurrence
    hipLaunchKernelGGL(k_prologue, dim3(256), dim3(256), 0, stream,
        QKOh + 8192, QKOl + 8192, (l == 0) ? OUT0 : dout, l, obh[0], obl[0]);
    for (int t = 0; t < 127; ++t) {
      hipLaunchKernelGGL(k_step, dim3(256), dim3(512), 0, stream,
          t, Wvo_hi, Wvo_lo, Wmx, QKOh + 8192, QKOl + 8192, VOb,
          obh[t & 1], obl[t & 1], obh[(t + 1) & 1], obl[(t + 1) & 1],
          (l == 0) ? OUT0 : dout, l);
    }
  }
}